// Round 1
// baseline (293.711 us; speedup 1.0000x reference)
//
#include <hip/hip_runtime.h>
#include <hip/hip_bf16.h>

typedef __bf16 bf8 __attribute__((ext_vector_type(8)));
typedef float  f4  __attribute__((ext_vector_type(4)));

#define RT 64   // batch rows per block
#define MS 4    // 16-row MFMA m-steps per tile

__device__ __forceinline__ float fsig(float v) {
    return 1.0f / (1.0f + __expf(-v));
}

__device__ __forceinline__ bf8 cvt8(f4 a, f4 b) {
    bf8 r;
    r[0] = (__bf16)a[0]; r[1] = (__bf16)a[1]; r[2] = (__bf16)a[2]; r[3] = (__bf16)a[3];
    r[4] = (__bf16)b[0]; r[5] = (__bf16)b[1]; r[6] = (__bf16)b[2]; r[7] = (__bf16)b[3];
    return r;
}

__global__ __launch_bounds__(512, 2) void lstm_fused_kernel(
    const float* __restrict__ x,   const float* __restrict__ h,
    const float* __restrict__ mem,
    const float* __restrict__ Wi,  const float* __restrict__ Wib,
    const float* __restrict__ Vi,  const float* __restrict__ Vib,
    const float* __restrict__ Wf,  const float* __restrict__ Wfb,
    const float* __restrict__ Vf,  const float* __restrict__ Vfb,
    const float* __restrict__ Wo,  const float* __restrict__ Wob,
    const float* __restrict__ Vo,  const float* __restrict__ Vob,
    float* __restrict__ out, long long Bn)
{
    // LDS tiles (bf16, XOR-swizzled on element-index bits 3..5)
    __shared__ __align__(16) __bf16 smX[RT * 64];    // 8 KB
    __shared__ __align__(16) __bf16 smH[RT * 128];   // 16 KB
    __shared__ __align__(16) __bf16 smG[RT * 128];   // 16 KB

    const int tid  = threadIdx.x;
    const int lane = tid & 63;
    const int wv   = tid >> 6;          // wave id 0..7
    const int c0   = wv * 16;           // this wave's output-column base
    const int b0   = blockIdx.x * RT;   // this block's batch-row base

    // Fragment lane mapping for mfma_f32_16x16x32_bf16:
    //   A: row = lane&15, k = (lane>>4)*8 + j   (8 contiguous k per lane)
    //   B: col = lane&15, k = (lane>>4)*8 + j
    //   C/D: col = lane&15, row = (lane>>4)*4 + reg   [m89-verified]
    const int nrow = c0 + (lane & 15);        // weight row (= output col) this lane serves
    const int kq   = (lane >> 4) << 3;        // k sub-offset 0,8,16,24

    // ---- weight B-fragments in registers (bf16); Vi re-used for the G pass ----
    bf8 BWi[2], BWf[2], BWo[2], BVi[4], BVf[4], BVo[4];
#pragma unroll
    for (int kf = 0; kf < 2; ++kf) {
        const float* p;
        p = Wi + nrow * 64 + kf * 32 + kq; BWi[kf] = cvt8(*(const f4*)p, *(const f4*)(p + 4));
        p = Wf + nrow * 64 + kf * 32 + kq; BWf[kf] = cvt8(*(const f4*)p, *(const f4*)(p + 4));
        p = Wo + nrow * 64 + kf * 32 + kq; BWo[kf] = cvt8(*(const f4*)p, *(const f4*)(p + 4));
    }
#pragma unroll
    for (int kf = 0; kf < 4; ++kf) {
        const float* p;
        p = Vi + nrow * 128 + kf * 32 + kq; BVi[kf] = cvt8(*(const f4*)p, *(const f4*)(p + 4));
        p = Vf + nrow * 128 + kf * 32 + kq; BVf[kf] = cvt8(*(const f4*)p, *(const f4*)(p + 4));
        p = Vo + nrow * 128 + kf * 32 + kq; BVo[kf] = cvt8(*(const f4*)p, *(const f4*)(p + 4));
    }

    // combined biases per output column (Wi_b+Vi_b serves both I and C)
    const float bsI = Wib[nrow] + Vib[nrow];
    const float bsF = Wfb[nrow] + Vfb[nrow];
    const float bsO = Wob[nrow] + Vob[nrow];

    // ---- stage x (64 cols) and h (128 cols) tiles to LDS as bf16, swizzled ----
    {
        const int rowx = tid >> 3, kbx = tid & 7;                 // 512 tasks = 64x8
        const float* p = x + (size_t)(b0 + rowx) * 64 + kbx * 8;
        bf8 v = cvt8(*(const f4*)p, *(const f4*)(p + 4));
        *(bf8*)&smX[rowx * 64 + ((kbx * 8) ^ ((rowx & 7) << 3))] = v;
#pragma unroll
        for (int ph = 0; ph < 2; ++ph) {                           // 1024 tasks = 64x16
            const int task = tid + ph * 512;
            const int rowh = task >> 4, kbh = task & 15;
            const float* q = h + (size_t)(b0 + rowh) * 128 + kbh * 8;
            bf8 u = cvt8(*(const f4*)q, *(const f4*)(q + 4));
            *(bf8*)&smH[rowh * 128 + ((kbh * 8) ^ ((rowh & 7) << 3))] = u;
        }
    }
    __syncthreads();

    // ---- phase A: wix, vih, preF, preO for the whole tile; G -> LDS ----
    f4 wixS[MS], FS[MS], IS[MS], OS[MS];
#pragma unroll
    for (int ms = 0; ms < MS; ++ms) {
        const int r0 = ms * 16;
        const int rA = r0 + (lane & 15);
        bf8 ax[2], ah[4];
#pragma unroll
        for (int kf = 0; kf < 2; ++kf)
            ax[kf] = *(const bf8*)&smX[rA * 64 + ((kf * 32 + kq) ^ ((rA & 7) << 3))];
#pragma unroll
        for (int kf = 0; kf < 4; ++kf)
            ah[kf] = *(const bf8*)&smH[rA * 128 + ((kf * 32 + kq) ^ ((rA & 7) << 3))];

        f4 wix = {0.f, 0.f, 0.f, 0.f};
        f4 vih = {0.f, 0.f, 0.f, 0.f};
        f4 pf  = {0.f, 0.f, 0.f, 0.f};
        f4 po  = {0.f, 0.f, 0.f, 0.f};
#pragma unroll
        for (int kf = 0; kf < 2; ++kf) {
            wix = __builtin_amdgcn_mfma_f32_16x16x32_bf16(ax[kf], BWi[kf], wix, 0, 0, 0);
            pf  = __builtin_amdgcn_mfma_f32_16x16x32_bf16(ax[kf], BWf[kf], pf,  0, 0, 0);
            po  = __builtin_amdgcn_mfma_f32_16x16x32_bf16(ax[kf], BWo[kf], po,  0, 0, 0);
        }
#pragma unroll
        for (int kf = 0; kf < 4; ++kf) {
            vih = __builtin_amdgcn_mfma_f32_16x16x32_bf16(ah[kf], BVi[kf], vih, 0, 0, 0);
            pf  = __builtin_amdgcn_mfma_f32_16x16x32_bf16(ah[kf], BVf[kf], pf,  0, 0, 0);
            po  = __builtin_amdgcn_mfma_f32_16x16x32_bf16(ah[kf], BVo[kf], po,  0, 0, 0);
        }

        f4 Fv, Iv, Ov;
#pragma unroll
        for (int i = 0; i < 4; ++i) {
            const float Fi = fsig(pf[i] + bsF);
            Fv[i] = Fi;
            Iv[i] = fsig(wix[i] + vih[i] + bsI);
            Ov[i] = fsig(po[i] + bsO);
            const int row = r0 + ((lane >> 4) << 2) + i;
            const int e   = row * 128 + (nrow ^ ((row & 7) << 3));
            const float hv = (float)smH[e];
            smG[e] = (__bf16)(Fi * hv);          // G = F * prev_hidden
        }
        wixS[ms] = wix; FS[ms] = Fv; IS[ms] = Iv; OS[ms] = Ov;
    }
    __syncthreads();

    // ---- phase B: vig = G @ Vi^T, then C, Ct, hidden, store ----
    const size_t outH = (size_t)Bn * 128;
#pragma unroll
    for (int ms = 0; ms < MS; ++ms) {
        const int r0 = ms * 16;
        const int rA = r0 + (lane & 15);
        f4 vig = {0.f, 0.f, 0.f, 0.f};
#pragma unroll
        for (int kf = 0; kf < 4; ++kf) {
            bf8 ag = *(const bf8*)&smG[rA * 128 + ((kf * 32 + kq) ^ ((rA & 7) << 3))];
            vig = __builtin_amdgcn_mfma_f32_16x16x32_bf16(ag, BVi[kf], vig, 0, 0, 0);
        }
#pragma unroll
        for (int i = 0; i < 4; ++i) {
            const float Cv  = fsig(wixS[ms][i] + vig[i] + bsI);
            const int   row = r0 + ((lane >> 4) << 2) + i;
            const size_t g  = (size_t)(b0 + row) * 128 + nrow;
            const float ct  = FS[ms][i] * mem[g] + IS[ms][i] * Cv;
            const float e2  = __expf(2.0f * ct);
            const float th  = 1.0f - 2.0f / (e2 + 1.0f);   // tanh(ct)
            out[g]        = ct;
            out[outH + g] = OS[ms][i] * th;
        }
    }
}

extern "C" void kernel_launch(void* const* d_in, const int* in_sizes, int n_in,
                              void* d_out, int out_size, void* d_ws, size_t ws_size,
                              hipStream_t stream) {
    const float* x   = (const float*)d_in[0];
    const float* h   = (const float*)d_in[1];
    const float* mem = (const float*)d_in[2];
    const float* Wi  = (const float*)d_in[3];
    const float* Wib = (const float*)d_in[4];
    const float* Vi  = (const float*)d_in[5];
    const float* Vib = (const float*)d_in[6];
    const float* Wf  = (const float*)d_in[7];
    const float* Wfb = (const float*)d_in[8];
    const float* Vf  = (const float*)d_in[9];
    const float* Vfb = (const float*)d_in[10];
    const float* Wo  = (const float*)d_in[11];
    const float* Wob = (const float*)d_in[12];
    const float* Vo  = (const float*)d_in[13];
    const float* Vob = (const float*)d_in[14];
    float* out = (float*)d_out;

    const long long Bn = (long long)(in_sizes[1] / 128);   // 262144
    const int blocks = (int)(Bn / RT);                     // 4096

    lstm_fused_kernel<<<blocks, 512, 0, stream>>>(
        x, h, mem, Wi, Wib, Vi, Vib, Wf, Wfb, Vf, Vfb, Wo, Wob, Vo, Vob, out, Bn);
}